// Round 3
// baseline (1070.542 us; speedup 1.0000x reference)
//
#include <hip/hip_runtime.h>
#include <hip/hip_bf16.h>

// Problem: B=2, S=2048, C=U=1024, H=16, dh=64. I/O FP32.
// Pipeline: cast X->bf16, transpose+cast W->bf16, QKV GEMM (bf16 MFMA, f16 out),
// transpose V -> [b,h,d,s] f16, barrier-free flash attention (f16 MFMA K=16,
// S^T/O^T register chaining, fp32 softmax/acc), fp32 residual + joint LN.

typedef __bf16 bf16_t;
typedef __bf16 bf16x8 __attribute__((ext_vector_type(8)));
typedef __bf16 bf16x4 __attribute__((ext_vector_type(4)));
typedef _Float16 f16_t;
typedef _Float16 f16x4 __attribute__((ext_vector_type(4)));
typedef float f32x4 __attribute__((ext_vector_type(4)));

constexpr int Bsz = 2;
constexpr int Seq = 2048;
constexpr int Cdim = 1024;   // == U
constexpr int Udim = 1024;
constexpr int Hn = 16;
constexpr int Dh = 64;
constexpr int Mrows = Bsz * Seq;          // 4096
constexpr int PerBatch = Seq * Udim;      // 2^21

// ---------------------------------------------------------------- cast X
__global__ __launch_bounds__(256)
void cast_x(const float* __restrict__ X, bf16_t* __restrict__ Xb)
{
    int i = blockIdx.x * 256 + threadIdx.x;     // over float4 groups, 1M total
    float4 v = ((const float4*)X)[i];
    bf16x4 o = { (bf16_t)v.x, (bf16_t)v.y, (bf16_t)v.z, (bf16_t)v.w };
    *(bf16x4*)(Xb + (size_t)i * 4) = o;
}

// ---------------------------------------------------------------- transpose W
// W[K=1024][N=1024] fp32 -> Wt[N][K] bf16; blockIdx.z selects q/k/v
__global__ void transpose_w(const float* __restrict__ Wq, const float* __restrict__ Wk,
                            const float* __restrict__ Wv,
                            bf16_t* __restrict__ Tq, bf16_t* __restrict__ Tk,
                            bf16_t* __restrict__ Tv)
{
    int z = blockIdx.z;
    const float* W = (z == 0) ? Wq : (z == 1) ? Wk : Wv;
    bf16_t* T = (z == 0) ? Tq : (z == 1) ? Tk : Tv;
    __shared__ bf16_t t[64][65];
    int x0 = blockIdx.x * 64, y0 = blockIdx.y * 64;
    int tx = threadIdx.x;
    for (int i = threadIdx.y; i < 64; i += 8)
        t[i][tx] = (bf16_t)W[(size_t)(y0 + i) * Cdim + x0 + tx];
    __syncthreads();
    for (int i = threadIdx.y; i < 64; i += 8)
        T[(size_t)(x0 + i) * Cdim + y0 + tx] = t[tx][i];
}

// ---------------------------------------------------------------- QKV GEMM
// C[4096][1024] = Xb @ W + bias (fp32), Wt[N][K] bf16. Output f16.
// 128x128 tile, 4 waves (2x2 of 64x64), BK=32, mfma 16x16x32 bf16.
__global__ __launch_bounds__(256)
void gemm_qkv(const bf16_t* __restrict__ X,
              const bf16_t* __restrict__ Wt0, const bf16_t* __restrict__ Wt1,
              const bf16_t* __restrict__ Wt2,
              const float* __restrict__ b0, const float* __restrict__ b1,
              const float* __restrict__ b2,
              f16_t* __restrict__ O0, f16_t* __restrict__ O1, f16_t* __restrict__ O2)
{
    int z = blockIdx.z;
    const bf16_t* Wt = (z == 0) ? Wt0 : (z == 1) ? Wt1 : Wt2;
    const float* bias = (z == 0) ? b0 : (z == 1) ? b1 : b2;
    f16_t* Og = (z == 0) ? O0 : (z == 1) ? O1 : O2;

    constexpr int Kd = 1024, Nd = 1024;
    __shared__ bf16_t As[128][40];   // +8 pad: 2-way bank alias only (free)
    __shared__ bf16_t Bs[128][40];

    int tid = threadIdx.x;
    int wave = tid >> 6, lane = tid & 63, quad = lane >> 4, l16 = lane & 15;
    int wm = (wave & 1) * 64, wn = (wave >> 1) * 64;
    int m0 = blockIdx.y * 128, n0 = blockIdx.x * 128;

    f32x4 acc[4][4] = {};

    int sr = tid >> 1, scol = (tid & 1) * 16;
    const bf16_t* Aptr = X + (size_t)(m0 + sr) * Kd + scol;
    const bf16_t* Bptr = Wt + (size_t)(n0 + sr) * Kd + scol;

    for (int k0 = 0; k0 < Kd; k0 += 32) {
        bf16x8 a0 = *(const bf16x8*)(Aptr + k0);
        bf16x8 a1 = *(const bf16x8*)(Aptr + k0 + 8);
        bf16x8 w0 = *(const bf16x8*)(Bptr + k0);
        bf16x8 w1 = *(const bf16x8*)(Bptr + k0 + 8);
        *(bf16x8*)&As[sr][scol] = a0;
        *(bf16x8*)&As[sr][scol + 8] = a1;
        *(bf16x8*)&Bs[sr][scol] = w0;
        *(bf16x8*)&Bs[sr][scol + 8] = w1;
        __syncthreads();

        bf16x8 af[4], bfr[4];
        for (int i = 0; i < 4; i++)
            af[i] = *(const bf16x8*)&As[wm + i * 16 + l16][quad * 8];
        for (int i = 0; i < 4; i++)
            bfr[i] = *(const bf16x8*)&Bs[wn + i * 16 + l16][quad * 8];
        for (int mt = 0; mt < 4; mt++)
            for (int nt = 0; nt < 4; nt++)
                acc[mt][nt] = __builtin_amdgcn_mfma_f32_16x16x32_bf16(
                    af[mt], bfr[nt], acc[mt][nt], 0, 0, 0);
        __syncthreads();
    }

    // epilogue: C/D layout col=lane&15, row=quad*4+reg
    for (int nt = 0; nt < 4; nt++) {
        int col = n0 + wn + nt * 16 + l16;
        float bv = bias[col];
        for (int mt = 0; mt < 4; mt++) {
            int row = m0 + wm + mt * 16 + quad * 4;
            for (int r = 0; r < 4; r++)
                Og[(size_t)(row + r) * Nd + col] = (f16_t)(acc[mt][nt][r] + bv);
        }
    }
}

// ---------------------------------------------------------------- transpose V
// V[4096][1024] f16 -> Vt[b][h][d=64][s=2048] f16
__global__ void transpose_v(const f16_t* __restrict__ V, f16_t* __restrict__ Vt)
{
    int s0 = blockIdx.x * 64;
    int y = blockIdx.y;                 // bh: b = y>>4, h = y&15
    int b = y >> 4, h = y & 15;
    __shared__ f16_t t[64][65];
    int tx = threadIdx.x;
    for (int i = threadIdx.y; i < 64; i += 8)
        t[i][tx] = V[(size_t)(b * Seq + s0 + i) * Udim + h * Dh + tx];
    __syncthreads();
    // t[s][d]; write Vt rows over d, contiguous in s
    for (int i = threadIdx.y; i < 64; i += 8)
        Vt[((size_t)y * Dh + i) * Seq + s0 + tx] = t[tx][i];
}

// ---------------------------------------------------------------- attention
// Barrier-free, no LDS. One wave per 16 q-rows. S^T = K.Q^T and O^T = V^T.P^T
// with v_mfma_f32_16x16x16f16: C/D layout [row=quad*4+r][col=l16] IS the
// B-operand layout [k=quad*4+j][n=l16] of the next MFMA -> P stays in regs.
__global__ __launch_bounds__(256)
void attn2(const f16_t* __restrict__ Q, const f16_t* __restrict__ K,
           const f16_t* __restrict__ Vt, float* __restrict__ O)
{
    int qtile = blockIdx.x, h = blockIdx.y, b = blockIdx.z;
    int tid = threadIdx.x;
    int w = tid >> 6, lane = tid & 63, quad = lane >> 4, l16 = lane & 15;
    int q0 = qtile * 64 + w * 16;                 // this wave's q rows
    size_t bS = (size_t)b * Seq;

    const f16_t* Qp = Q + (bS + q0 + l16) * Udim + h * Dh + quad * 4;
    const f16_t* Kp = K + bS * Udim + h * Dh + quad * 4;
    const f16_t* Vp = Vt + ((size_t)(b * Hn + h)) * Dh * Seq;

    // Q B-fragments: B[k=d=quad*4+j][n=q=l16], 4 d-16 groups
    f16x4 qf[4];
    for (int s = 0; s < 4; s++) qf[s] = *(const f16x4*)(Qp + s * 16);

    f32x4 Oacc[4] = {};          // O^T tiles: d = dt*16+quad*4+r, q = l16
    float m = -1e30f, l = 0.0f;  // per-lane: one q row

    for (int kv0 = 0; kv0 <= qtile * 64; kv0 += 64) {
        bool diag = (kv0 == qtile * 64);
        int tmax = diag ? (w + 1) : 4;    // t>w fully masked on diagonal block

        // S^T tiles: A=K[m=kv][k=d], B=Q^T
        f32x4 st[4];
        for (int t = 0; t < tmax; t++) {
            f32x4 a = {};
            const f16_t* kp = Kp + (size_t)(kv0 + t * 16 + l16) * Udim;
            for (int s = 0; s < 4; s++) {
                f16x4 kf = *(const f16x4*)(kp + s * 16);
                a = __builtin_amdgcn_mfma_f32_16x16x16f16(kf, qf[s], a, 0, 0, 0);
            }
            st[t] = a;
        }

        // softmax: row = q = l16 (per-lane scalar state)
        float mx = -1e30f;
        for (int t = 0; t < tmax; t++)
            for (int r = 0; r < 4; r++) {
                float sv = st[t][r] * 0.125f;
                if (diag && t == w && (kv0 + t * 16 + quad * 4 + r > q0 + l16))
                    sv = -1e30f;     // causal
                st[t][r] = sv;
                mx = fmaxf(mx, sv);
            }
        mx = fmaxf(mx, __shfl_xor(mx, 16));
        mx = fmaxf(mx, __shfl_xor(mx, 32));
        float mnew = fmaxf(m, mx);
        float alpha = __expf(m - mnew);
        float sum = 0.0f;
        f16x4 pf[4];
        for (int t = 0; t < tmax; t++)
            for (int r = 0; r < 4; r++) {
                float p = __expf(st[t][r] - mnew);
                sum += p;
                pf[t][r] = (f16_t)p;   // P^T B-fragment, directly from C layout
            }
        sum += __shfl_xor(sum, 16);
        sum += __shfl_xor(sum, 32);
        l = l * alpha + sum;
        m = mnew;
        for (int dt = 0; dt < 4; dt++)
            for (int r = 0; r < 4; r++) Oacc[dt][r] *= alpha;

        // O^T += V^T . P^T : A = Vt[m=d][k=kv]
        for (int dt = 0; dt < 4; dt++) {
            const f16_t* vp = Vp + (size_t)(dt * 16 + l16) * Seq + kv0 + quad * 4;
            for (int t = 0; t < tmax; t++) {
                f16x4 vf = *(const f16x4*)(vp + t * 16);
                Oacc[dt] = __builtin_amdgcn_mfma_f32_16x16x16f16(vf, pf[t], Oacc[dt], 0, 0, 0);
            }
        }
    }

    // epilogue: lane holds O^T[d=dt*16+quad*4+(0..3)][q=l16] -> float4 stores
    float invl = 1.0f / l;
    float* Op = O + (bS + q0 + l16) * Udim + h * Dh;
    for (int dt = 0; dt < 4; dt++) {
        f32x4 o = Oacc[dt] * invl;
        *(f32x4*)(Op + dt * 16 + quad * 4) = o;
    }
}

// ---------------------------------------------------------------- LN stats
__global__ __launch_bounds__(256)
void ln_stats(const float* __restrict__ attn, const float* __restrict__ X,
              float* __restrict__ stats)
{
    int b = blockIdx.y;
    int base = b * PerBatch + blockIdx.x * 2048 + threadIdx.x * 8;
    float s = 0.0f, ss = 0.0f;
    for (int v = 0; v < 2; v++) {
        float4 a = *(const float4*)(attn + base + v * 4);
        float4 x = *(const float4*)(X + base + v * 4);
        float t0 = a.x + x.x, t1 = a.y + x.y, t2 = a.z + x.z, t3 = a.w + x.w;
        s += t0 + t1 + t2 + t3;
        ss += t0 * t0 + t1 * t1 + t2 * t2 + t3 * t3;
    }
    for (int o = 1; o < 64; o <<= 1) { s += __shfl_xor(s, o); ss += __shfl_xor(ss, o); }
    __shared__ float red[8];
    int wave = threadIdx.x >> 6, lane = threadIdx.x & 63;
    if (lane == 0) { red[wave] = s; red[4 + wave] = ss; }
    __syncthreads();
    if (threadIdx.x == 0) {
        atomicAdd(&stats[b], red[0] + red[1] + red[2] + red[3]);
        atomicAdd(&stats[2 + b], red[4] + red[5] + red[6] + red[7]);
    }
}

// ---------------------------------------------------------------- LN apply
__global__ __launch_bounds__(256)
void ln_norm(const float* __restrict__ attn, const float* __restrict__ X,
             const float* __restrict__ gamma, const float* __restrict__ beta,
             const float* __restrict__ stats, float* __restrict__ out)
{
    constexpr int TOT4 = Bsz * Seq * Udim / 4;   // 1M float4
    constexpr float invN = 1.0f / (float)PerBatch;
    float mu[2], inv[2];
    for (int b = 0; b < 2; b++) {
        float m = stats[b] * invN;
        float var = stats[2 + b] * invN - m * m;
        mu[b] = m;
        inv[b] = rsqrtf(var + 1e-5f);
    }
    for (int i = blockIdx.x * blockDim.x + threadIdx.x; i < TOT4;
         i += gridDim.x * blockDim.x) {
        int f = i * 4;
        int b = f >> 21;
        int su = f & (PerBatch - 1);
        float4 a = *(const float4*)(attn + f);
        float4 x = *(const float4*)(X + f);
        float4 g = *(const float4*)(gamma + su);
        float4 be = *(const float4*)(beta + su);
        float4 o;
        o.x = (a.x + x.x - mu[b]) * inv[b] * g.x + be.x;
        o.y = (a.y + x.y - mu[b]) * inv[b] * g.y + be.y;
        o.z = (a.z + x.z - mu[b]) * inv[b] * g.z + be.z;
        o.w = (a.w + x.w - mu[b]) * inv[b] * g.w + be.w;
        *(float4*)(out + f) = o;
    }
}

// ---------------------------------------------------------------- launch
extern "C" void kernel_launch(void* const* d_in, const int* in_sizes, int n_in,
                              void* d_out, int out_size, void* d_ws, size_t ws_size,
                              hipStream_t stream)
{
    const float* X     = (const float*)d_in[0];
    const float* Wq    = (const float*)d_in[1];
    const float* bq    = (const float*)d_in[2];
    const float* Wk    = (const float*)d_in[3];
    const float* bk    = (const float*)d_in[4];
    const float* Wv    = (const float*)d_in[5];
    const float* bv    = (const float*)d_in[6];
    const float* gamma = (const float*)d_in[7];
    const float* beta  = (const float*)d_in[8];
    float* out = (float*)d_out;

    char* ws = (char*)d_ws;
    size_t off = 0;
    auto alloc = [&](size_t bytes) -> void* {
        void* p = ws + off;
        off += (bytes + 255) & ~(size_t)255;
        return p;
    };
    bf16_t* Xb = (bf16_t*)alloc((size_t)Mrows * Cdim * 2);
    bf16_t* Tq = (bf16_t*)alloc((size_t)Cdim * Udim * 2);
    bf16_t* Tk = (bf16_t*)alloc((size_t)Cdim * Udim * 2);
    bf16_t* Tv = (bf16_t*)alloc((size_t)Cdim * Udim * 2);
    f16_t*  Qb = (f16_t*)alloc((size_t)Mrows * Udim * 2);
    f16_t*  Kb = (f16_t*)alloc((size_t)Mrows * Udim * 2);
    f16_t*  Vb = (f16_t*)alloc((size_t)Mrows * Udim * 2);
    f16_t*  Vtb = (f16_t*)alloc((size_t)Mrows * Udim * 2);
    float*  Ab = (float*)alloc((size_t)Mrows * Udim * 4);
    float*  stats = (float*)alloc(4 * sizeof(float));

    hipMemsetAsync(stats, 0, 4 * sizeof(float), stream);
    cast_x<<<dim3(Mrows * Cdim / 4 / 256), 256, 0, stream>>>(X, Xb);
    transpose_w<<<dim3(16, 16, 3), dim3(64, 8), 0, stream>>>(Wq, Wk, Wv, Tq, Tk, Tv);
    gemm_qkv<<<dim3(8, 32, 3), 256, 0, stream>>>(Xb, Tq, Tk, Tv, bq, bk, bv, Qb, Kb, Vb);
    transpose_v<<<dim3(Seq / 64, Bsz * Hn), dim3(64, 8), 0, stream>>>(Vb, Vtb);
    attn2<<<dim3(Seq / 64, Hn, Bsz), 256, 0, stream>>>(Qb, Kb, Vtb, Ab);
    ln_stats<<<dim3(1024, 2), 256, 0, stream>>>(Ab, X, stats);
    ln_norm<<<dim3(1024), 256, 0, stream>>>(Ab, X, gamma, beta, stats, out);
}

// Round 4
// 1060.151 us; speedup vs baseline: 1.0098x; 1.0098x over previous
//
#include <hip/hip_runtime.h>
#include <hip/hip_bf16.h>

// Problem: B=2, S=2048, C=U=1024, H=16, dh=64. I/O FP32.
// Pipeline: cast X->bf16, transpose+cast W->bf16, QKV GEMM (bf16 MFMA, f16 out),
// transpose V -> [b,h,d,s] f16, flash attention (LDS-staged K/V tiles, S^T/O^T
// register chaining via f16 MFMA, fp32 softmax/acc), fp32 residual + joint LN.

typedef __bf16 bf16_t;
typedef __bf16 bf16x8 __attribute__((ext_vector_type(8)));
typedef __bf16 bf16x4 __attribute__((ext_vector_type(4)));
typedef _Float16 f16_t;
typedef _Float16 f16x4 __attribute__((ext_vector_type(4)));
typedef _Float16 f16x8 __attribute__((ext_vector_type(8)));
typedef float f32x4 __attribute__((ext_vector_type(4)));

constexpr int Bsz = 2;
constexpr int Seq = 2048;
constexpr int Cdim = 1024;   // == U
constexpr int Udim = 1024;
constexpr int Hn = 16;
constexpr int Dh = 64;
constexpr int Mrows = Bsz * Seq;          // 4096
constexpr int PerBatch = Seq * Udim;      // 2^21

// ---------------------------------------------------------------- cast X
__global__ __launch_bounds__(256)
void cast_x(const float* __restrict__ X, bf16_t* __restrict__ Xb)
{
    int i = blockIdx.x * 256 + threadIdx.x;     // over float4 groups, 1M total
    float4 v = ((const float4*)X)[i];
    bf16x4 o = { (bf16_t)v.x, (bf16_t)v.y, (bf16_t)v.z, (bf16_t)v.w };
    *(bf16x4*)(Xb + (size_t)i * 4) = o;
}

// ---------------------------------------------------------------- transpose W
// W[K=1024][N=1024] fp32 -> Wt[N][K] bf16; blockIdx.z selects q/k/v
__global__ void transpose_w(const float* __restrict__ Wq, const float* __restrict__ Wk,
                            const float* __restrict__ Wv,
                            bf16_t* __restrict__ Tq, bf16_t* __restrict__ Tk,
                            bf16_t* __restrict__ Tv)
{
    int z = blockIdx.z;
    const float* W = (z == 0) ? Wq : (z == 1) ? Wk : Wv;
    bf16_t* T = (z == 0) ? Tq : (z == 1) ? Tk : Tv;
    __shared__ bf16_t t[64][65];
    int x0 = blockIdx.x * 64, y0 = blockIdx.y * 64;
    int tx = threadIdx.x;
    for (int i = threadIdx.y; i < 64; i += 8)
        t[i][tx] = (bf16_t)W[(size_t)(y0 + i) * Cdim + x0 + tx];
    __syncthreads();
    for (int i = threadIdx.y; i < 64; i += 8)
        T[(size_t)(x0 + i) * Cdim + y0 + tx] = t[tx][i];
}

// ---------------------------------------------------------------- QKV GEMM
// C[4096][1024] = Xb @ W + bias (fp32), Wt[N][K] bf16. Output f16.
// 128x128 tile, 4 waves (2x2 of 64x64), BK=32, mfma 16x16x32 bf16.
__global__ __launch_bounds__(256)
void gemm_qkv(const bf16_t* __restrict__ X,
              const bf16_t* __restrict__ Wt0, const bf16_t* __restrict__ Wt1,
              const bf16_t* __restrict__ Wt2,
              const float* __restrict__ b0, const float* __restrict__ b1,
              const float* __restrict__ b2,
              f16_t* __restrict__ O0, f16_t* __restrict__ O1, f16_t* __restrict__ O2)
{
    int z = blockIdx.z;
    const bf16_t* Wt = (z == 0) ? Wt0 : (z == 1) ? Wt1 : Wt2;
    const float* bias = (z == 0) ? b0 : (z == 1) ? b1 : b2;
    f16_t* Og = (z == 0) ? O0 : (z == 1) ? O1 : O2;

    constexpr int Kd = 1024, Nd = 1024;
    __shared__ bf16_t As[128][40];   // +8 pad: 2-way bank alias only (free)
    __shared__ bf16_t Bs[128][40];

    int tid = threadIdx.x;
    int wave = tid >> 6, lane = tid & 63, quad = lane >> 4, l16 = lane & 15;
    int wm = (wave & 1) * 64, wn = (wave >> 1) * 64;
    int m0 = blockIdx.y * 128, n0 = blockIdx.x * 128;

    f32x4 acc[4][4] = {};

    int sr = tid >> 1, scol = (tid & 1) * 16;
    const bf16_t* Aptr = X + (size_t)(m0 + sr) * Kd + scol;
    const bf16_t* Bptr = Wt + (size_t)(n0 + sr) * Kd + scol;

    for (int k0 = 0; k0 < Kd; k0 += 32) {
        bf16x8 a0 = *(const bf16x8*)(Aptr + k0);
        bf16x8 a1 = *(const bf16x8*)(Aptr + k0 + 8);
        bf16x8 w0 = *(const bf16x8*)(Bptr + k0);
        bf16x8 w1 = *(const bf16x8*)(Bptr + k0 + 8);
        *(bf16x8*)&As[sr][scol] = a0;
        *(bf16x8*)&As[sr][scol + 8] = a1;
        *(bf16x8*)&Bs[sr][scol] = w0;
        *(bf16x8*)&Bs[sr][scol + 8] = w1;
        __syncthreads();

        bf16x8 af[4], bfr[4];
        for (int i = 0; i < 4; i++)
            af[i] = *(const bf16x8*)&As[wm + i * 16 + l16][quad * 8];
        for (int i = 0; i < 4; i++)
            bfr[i] = *(const bf16x8*)&Bs[wn + i * 16 + l16][quad * 8];
        for (int mt = 0; mt < 4; mt++)
            for (int nt = 0; nt < 4; nt++)
                acc[mt][nt] = __builtin_amdgcn_mfma_f32_16x16x32_bf16(
                    af[mt], bfr[nt], acc[mt][nt], 0, 0, 0);
        __syncthreads();
    }

    // epilogue: C/D layout col=lane&15, row=quad*4+reg
    for (int nt = 0; nt < 4; nt++) {
        int col = n0 + wn + nt * 16 + l16;
        float bv = bias[col];
        for (int mt = 0; mt < 4; mt++) {
            int row = m0 + wm + mt * 16 + quad * 4;
            for (int r = 0; r < 4; r++)
                Og[(size_t)(row + r) * Nd + col] = (f16_t)(acc[mt][nt][r] + bv);
        }
    }
}

// ---------------------------------------------------------------- transpose V
// V[4096][1024] f16 -> Vt[b][h][d=64][s=2048] f16
__global__ void transpose_v(const f16_t* __restrict__ V, f16_t* __restrict__ Vt)
{
    int s0 = blockIdx.x * 64;
    int y = blockIdx.y;                 // bh: b = y>>4, h = y&15
    int b = y >> 4, h = y & 15;
    __shared__ f16_t t[64][65];
    int tx = threadIdx.x;
    for (int i = threadIdx.y; i < 64; i += 8)
        t[i][tx] = V[(size_t)(b * Seq + s0 + i) * Udim + h * Dh + tx];
    __syncthreads();
    // t[s][d]; write Vt rows over d, contiguous in s
    for (int i = threadIdx.y; i < 64; i += 8)
        Vt[((size_t)y * Dh + i) * Seq + s0 + tx] = t[tx][i];
}

// ---------------------------------------------------------------- attention
// LDS-staged K/V tiles + S^T/O^T register chaining. 4 waves, each 16 q rows.
// S^T = K.Q^T via mfma 16x16x32_f16; P^T stays in registers (C layout == PV
// B-operand layout at K=16); O^T += V^T.P^T via mfma 16x16x16f16.
__global__ __launch_bounds__(256)
void attn3(const f16_t* __restrict__ Q, const f16_t* __restrict__ K,
           const f16_t* __restrict__ Vt, float* __restrict__ O)
{
    int qtile = blockIdx.x, h = blockIdx.y, b = blockIdx.z;
    int tid = threadIdx.x;
    int w = tid >> 6, lane = tid & 63, quad = lane >> 4, l16 = lane & 15;
    int q0 = qtile * 64 + w * 16;                 // this wave's q rows
    size_t bS = (size_t)b * Seq;

    __shared__ f16_t Ks[64][72];   // [kv][d]
    __shared__ f16_t Vs[64][72];   // [d][kv]

    // Q B-fragments (16x16x32): B[k=d=s*32+quad*8+j][n=q=l16]
    const f16_t* Qp = Q + (bS + q0 + l16) * Udim + h * Dh;
    f16x8 qf[2];
    for (int s = 0; s < 2; s++) qf[s] = *(const f16x8*)(Qp + s * 32 + quad * 8);

    const f16_t* Kg = K + bS * Udim + h * Dh;
    const f16_t* Vg = Vt + ((size_t)(b * Hn + h)) * Dh * Seq;

    f32x4 Oacc[4] = {};          // O^T tiles: d = dt*16+quad*4+r, q = l16
    float m = -1e30f, l = 0.0f;  // per-lane: one q row

    int sr = tid >> 2, sc = (tid & 3) * 16;
    for (int kv0 = 0; kv0 <= qtile * 64; kv0 += 64) {
        // stage K-tile [kv][d] and V-tile [d][kv] (both coalesced 32B/thread)
        {
            const f16_t* kp = Kg + (size_t)(kv0 + sr) * Udim + sc;
            f16x8 k0 = *(const f16x8*)kp;
            f16x8 k1 = *(const f16x8*)(kp + 8);
            const f16_t* vp = Vg + (size_t)sr * Seq + kv0 + sc;
            f16x8 v0 = *(const f16x8*)vp;
            f16x8 v1 = *(const f16x8*)(vp + 8);
            *(f16x8*)&Ks[sr][sc] = k0;
            *(f16x8*)&Ks[sr][sc + 8] = k1;
            *(f16x8*)&Vs[sr][sc] = v0;
            *(f16x8*)&Vs[sr][sc + 8] = v1;
        }
        __syncthreads();

        bool diag = (kv0 == qtile * 64);
        int tmax = diag ? (w + 1) : 4;    // tiles t>w fully masked on diagonal

        // S^T tiles: A=K[m=kv][k=d] from LDS, B=Q^T from regs
        f32x4 st[4];
        for (int t = 0; t < tmax; t++) {
            f32x4 a = {};
            for (int s = 0; s < 2; s++) {
                f16x8 kf = *(const f16x8*)&Ks[t * 16 + l16][s * 32 + quad * 8];
                a = __builtin_amdgcn_mfma_f32_16x16x32_f16(kf, qf[s], a, 0, 0, 0);
            }
            st[t] = a;
        }

        // softmax: row = q = l16 (per-lane scalar state)
        float mx = -1e30f;
        for (int t = 0; t < tmax; t++)
            for (int r = 0; r < 4; r++) {
                float sv = st[t][r] * 0.125f;
                if (diag && t == w && (kv0 + t * 16 + quad * 4 + r > q0 + l16))
                    sv = -1e30f;     // causal
                st[t][r] = sv;
                mx = fmaxf(mx, sv);
            }
        mx = fmaxf(mx, __shfl_xor(mx, 16));
        mx = fmaxf(mx, __shfl_xor(mx, 32));
        float mnew = fmaxf(m, mx);
        float alpha = __expf(m - mnew);
        float sum = 0.0f;
        f16x4 pf[4];
        for (int t = 0; t < tmax; t++)
            for (int r = 0; r < 4; r++) {
                float p = __expf(st[t][r] - mnew);
                sum += p;
                pf[t][r] = (f16_t)p;   // P^T B-fragment, direct from C layout
            }
        sum += __shfl_xor(sum, 16);
        sum += __shfl_xor(sum, 32);
        l = l * alpha + sum;
        m = mnew;
        for (int dt = 0; dt < 4; dt++)
            for (int r = 0; r < 4; r++) Oacc[dt][r] *= alpha;

        // O^T += V^T . P^T : A = Vs[m=d][k=kv] from LDS
        for (int dt = 0; dt < 4; dt++) {
            for (int t = 0; t < tmax; t++) {
                f16x4 vf = *(const f16x4*)&Vs[dt * 16 + l16][t * 16 + quad * 4];
                Oacc[dt] = __builtin_amdgcn_mfma_f32_16x16x16f16(vf, pf[t], Oacc[dt], 0, 0, 0);
            }
        }
        __syncthreads();   // LDS reads done before next staging
    }

    // epilogue: lane holds O^T[d=dt*16+quad*4+(0..3)][q=l16] -> float4 stores
    float invl = 1.0f / l;
    float* Op = O + (bS + q0 + l16) * Udim + h * Dh;
    for (int dt = 0; dt < 4; dt++) {
        f32x4 o = Oacc[dt] * invl;
        *(f32x4*)(Op + dt * 16 + quad * 4) = o;
    }
}

// ---------------------------------------------------------------- LN stats
__global__ __launch_bounds__(256)
void ln_stats(const float* __restrict__ attn, const float* __restrict__ X,
              float* __restrict__ stats)
{
    int b = blockIdx.y;
    int base = b * PerBatch + blockIdx.x * 2048 + threadIdx.x * 8;
    float s = 0.0f, ss = 0.0f;
    for (int v = 0; v < 2; v++) {
        float4 a = *(const float4*)(attn + base + v * 4);
        float4 x = *(const float4*)(X + base + v * 4);
        float t0 = a.x + x.x, t1 = a.y + x.y, t2 = a.z + x.z, t3 = a.w + x.w;
        s += t0 + t1 + t2 + t3;
        ss += t0 * t0 + t1 * t1 + t2 * t2 + t3 * t3;
    }
    for (int o = 1; o < 64; o <<= 1) { s += __shfl_xor(s, o); ss += __shfl_xor(ss, o); }
    __shared__ float red[8];
    int wave = threadIdx.x >> 6, lane = threadIdx.x & 63;
    if (lane == 0) { red[wave] = s; red[4 + wave] = ss; }
    __syncthreads();
    if (threadIdx.x == 0) {
        atomicAdd(&stats[b], red[0] + red[1] + red[2] + red[3]);
        atomicAdd(&stats[2 + b], red[4] + red[5] + red[6] + red[7]);
    }
}

// ---------------------------------------------------------------- LN apply
__global__ __launch_bounds__(256)
void ln_norm(const float* __restrict__ attn, const float* __restrict__ X,
             const float* __restrict__ gamma, const float* __restrict__ beta,
             const float* __restrict__ stats, float* __restrict__ out)
{
    constexpr int TOT4 = Bsz * Seq * Udim / 4;   // 1M float4
    constexpr float invN = 1.0f / (float)PerBatch;
    float mu[2], inv[2];
    for (int b = 0; b < 2; b++) {
        float m = stats[b] * invN;
        float var = stats[2 + b] * invN - m * m;
        mu[b] = m;
        inv[b] = rsqrtf(var + 1e-5f);
    }
    for (int i = blockIdx.x * blockDim.x + threadIdx.x; i < TOT4;
         i += gridDim.x * blockDim.x) {
        int f = i * 4;
        int b = f >> 21;
        int su = f & (PerBatch - 1);
        float4 a = *(const float4*)(attn + f);
        float4 x = *(const float4*)(X + f);
        float4 g = *(const float4*)(gamma + su);
        float4 be = *(const float4*)(beta + su);
        float4 o;
        o.x = (a.x + x.x - mu[b]) * inv[b] * g.x + be.x;
        o.y = (a.y + x.y - mu[b]) * inv[b] * g.y + be.y;
        o.z = (a.z + x.z - mu[b]) * inv[b] * g.z + be.z;
        o.w = (a.w + x.w - mu[b]) * inv[b] * g.w + be.w;
        *(float4*)(out + f) = o;
    }
}

// ---------------------------------------------------------------- launch
extern "C" void kernel_launch(void* const* d_in, const int* in_sizes, int n_in,
                              void* d_out, int out_size, void* d_ws, size_t ws_size,
                              hipStream_t stream)
{
    const float* X     = (const float*)d_in[0];
    const float* Wq    = (const float*)d_in[1];
    const float* bq    = (const float*)d_in[2];
    const float* Wk    = (const float*)d_in[3];
    const float* bk    = (const float*)d_in[4];
    const float* Wv    = (const float*)d_in[5];
    const float* bv    = (const float*)d_in[6];
    const float* gamma = (const float*)d_in[7];
    const float* beta  = (const float*)d_in[8];
    float* out = (float*)d_out;

    char* ws = (char*)d_ws;
    size_t off = 0;
    auto alloc = [&](size_t bytes) -> void* {
        void* p = ws + off;
        off += (bytes + 255) & ~(size_t)255;
        return p;
    };
    bf16_t* Xb = (bf16_t*)alloc((size_t)Mrows * Cdim * 2);
    bf16_t* Tq = (bf16_t*)alloc((size_t)Cdim * Udim * 2);
    bf16_t* Tk = (bf16_t*)alloc((size_t)Cdim * Udim * 2);
    bf16_t* Tv = (bf16_t*)alloc((size_t)Cdim * Udim * 2);
    f16_t*  Qb = (f16_t*)alloc((size_t)Mrows * Udim * 2);
    f16_t*  Kb = (f16_t*)alloc((size_t)Mrows * Udim * 2);
    f16_t*  Vb = (f16_t*)alloc((size_t)Mrows * Udim * 2);
    f16_t*  Vtb = (f16_t*)alloc((size_t)Mrows * Udim * 2);
    float*  Ab = (float*)alloc((size_t)Mrows * Udim * 4);
    float*  stats = (float*)alloc(4 * sizeof(float));

    hipMemsetAsync(stats, 0, 4 * sizeof(float), stream);
    cast_x<<<dim3(Mrows * Cdim / 4 / 256), 256, 0, stream>>>(X, Xb);
    transpose_w<<<dim3(16, 16, 3), dim3(64, 8), 0, stream>>>(Wq, Wk, Wv, Tq, Tk, Tv);
    gemm_qkv<<<dim3(8, 32, 3), 256, 0, stream>>>(Xb, Tq, Tk, Tv, bq, bk, bv, Qb, Kb, Vb);
    transpose_v<<<dim3(Seq / 64, Bsz * Hn), dim3(64, 8), 0, stream>>>(Vb, Vtb);
    attn3<<<dim3(Seq / 64, Hn, Bsz), 256, 0, stream>>>(Qb, Kb, Vtb, Ab);
    ln_stats<<<dim3(1024, 2), 256, 0, stream>>>(Ab, X, stats);
    ln_norm<<<dim3(1024), 256, 0, stream>>>(Ab, X, gamma, beta, stats, out);
}

// Round 5
// 310.879 us; speedup vs baseline: 3.4436x; 3.4102x over previous
//
#include <hip/hip_runtime.h>
#include <hip/hip_bf16.h>

// Problem: B=2, S=2048, C=U=1024, H=16, dh=64. I/O FP32.
// Pipeline: cast X->bf16, transpose+cast W->bf16, QKV GEMM (bf16 MFMA, f16 out),
// transpose V -> [b,h,d,s] f16, flash attention (LDS-staged K/V tiles, S^T/O^T
// register chaining via f16 MFMA, STATIC loop bounds -> all-register frags),
// fp32 residual + joint LN.

typedef __bf16 bf16_t;
typedef __bf16 bf16x8 __attribute__((ext_vector_type(8)));
typedef __bf16 bf16x4 __attribute__((ext_vector_type(4)));
typedef _Float16 f16_t;
typedef _Float16 f16x4 __attribute__((ext_vector_type(4)));
typedef _Float16 f16x8 __attribute__((ext_vector_type(8)));
typedef float f32x4 __attribute__((ext_vector_type(4)));

constexpr int Bsz = 2;
constexpr int Seq = 2048;
constexpr int Cdim = 1024;   // == U
constexpr int Udim = 1024;
constexpr int Hn = 16;
constexpr int Dh = 64;
constexpr int Mrows = Bsz * Seq;          // 4096
constexpr int PerBatch = Seq * Udim;      // 2^21

// ---------------------------------------------------------------- cast X
__global__ __launch_bounds__(256)
void cast_x(const float* __restrict__ X, bf16_t* __restrict__ Xb)
{
    int i = blockIdx.x * 256 + threadIdx.x;     // over float4 groups, 1M total
    float4 v = ((const float4*)X)[i];
    bf16x4 o = { (bf16_t)v.x, (bf16_t)v.y, (bf16_t)v.z, (bf16_t)v.w };
    *(bf16x4*)(Xb + (size_t)i * 4) = o;
}

// ---------------------------------------------------------------- transpose W
// W[K=1024][N=1024] fp32 -> Wt[N][K] bf16; blockIdx.z selects q/k/v
__global__ void transpose_w(const float* __restrict__ Wq, const float* __restrict__ Wk,
                            const float* __restrict__ Wv,
                            bf16_t* __restrict__ Tq, bf16_t* __restrict__ Tk,
                            bf16_t* __restrict__ Tv)
{
    int z = blockIdx.z;
    const float* W = (z == 0) ? Wq : (z == 1) ? Wk : Wv;
    bf16_t* T = (z == 0) ? Tq : (z == 1) ? Tk : Tv;
    __shared__ bf16_t t[64][65];
    int x0 = blockIdx.x * 64, y0 = blockIdx.y * 64;
    int tx = threadIdx.x;
    for (int i = threadIdx.y; i < 64; i += 8)
        t[i][tx] = (bf16_t)W[(size_t)(y0 + i) * Cdim + x0 + tx];
    __syncthreads();
    for (int i = threadIdx.y; i < 64; i += 8)
        T[(size_t)(x0 + i) * Cdim + y0 + tx] = t[tx][i];
}

// ---------------------------------------------------------------- QKV GEMM
// C[4096][1024] = Xb @ W + bias (fp32), Wt[N][K] bf16. Output f16.
// 128x128 tile, 4 waves (2x2 of 64x64), BK=32, mfma 16x16x32 bf16.
__global__ __launch_bounds__(256)
void gemm_qkv(const bf16_t* __restrict__ X,
              const bf16_t* __restrict__ Wt0, const bf16_t* __restrict__ Wt1,
              const bf16_t* __restrict__ Wt2,
              const float* __restrict__ b0, const float* __restrict__ b1,
              const float* __restrict__ b2,
              f16_t* __restrict__ O0, f16_t* __restrict__ O1, f16_t* __restrict__ O2)
{
    int z = blockIdx.z;
    const bf16_t* Wt = (z == 0) ? Wt0 : (z == 1) ? Wt1 : Wt2;
    const float* bias = (z == 0) ? b0 : (z == 1) ? b1 : b2;
    f16_t* Og = (z == 0) ? O0 : (z == 1) ? O1 : O2;

    constexpr int Kd = 1024, Nd = 1024;
    __shared__ bf16_t As[128][40];   // +8 pad: 2-way bank alias only (free)
    __shared__ bf16_t Bs[128][40];

    int tid = threadIdx.x;
    int wave = tid >> 6, lane = tid & 63, quad = lane >> 4, l16 = lane & 15;
    int wm = (wave & 1) * 64, wn = (wave >> 1) * 64;
    int m0 = blockIdx.y * 128, n0 = blockIdx.x * 128;

    f32x4 acc[4][4] = {};

    int sr = tid >> 1, scol = (tid & 1) * 16;
    const bf16_t* Aptr = X + (size_t)(m0 + sr) * Kd + scol;
    const bf16_t* Bptr = Wt + (size_t)(n0 + sr) * Kd + scol;

    for (int k0 = 0; k0 < Kd; k0 += 32) {
        bf16x8 a0 = *(const bf16x8*)(Aptr + k0);
        bf16x8 a1 = *(const bf16x8*)(Aptr + k0 + 8);
        bf16x8 w0 = *(const bf16x8*)(Bptr + k0);
        bf16x8 w1 = *(const bf16x8*)(Bptr + k0 + 8);
        *(bf16x8*)&As[sr][scol] = a0;
        *(bf16x8*)&As[sr][scol + 8] = a1;
        *(bf16x8*)&Bs[sr][scol] = w0;
        *(bf16x8*)&Bs[sr][scol + 8] = w1;
        __syncthreads();

        bf16x8 af[4], bfr[4];
#pragma unroll
        for (int i = 0; i < 4; i++)
            af[i] = *(const bf16x8*)&As[wm + i * 16 + l16][quad * 8];
#pragma unroll
        for (int i = 0; i < 4; i++)
            bfr[i] = *(const bf16x8*)&Bs[wn + i * 16 + l16][quad * 8];
#pragma unroll
        for (int mt = 0; mt < 4; mt++)
#pragma unroll
            for (int nt = 0; nt < 4; nt++)
                acc[mt][nt] = __builtin_amdgcn_mfma_f32_16x16x32_bf16(
                    af[mt], bfr[nt], acc[mt][nt], 0, 0, 0);
        __syncthreads();
    }

    // epilogue: C/D layout col=lane&15, row=quad*4+reg
#pragma unroll
    for (int nt = 0; nt < 4; nt++) {
        int col = n0 + wn + nt * 16 + l16;
        float bv = bias[col];
#pragma unroll
        for (int mt = 0; mt < 4; mt++) {
            int row = m0 + wm + mt * 16 + quad * 4;
#pragma unroll
            for (int r = 0; r < 4; r++)
                Og[(size_t)(row + r) * Nd + col] = (f16_t)(acc[mt][nt][r] + bv);
        }
    }
}

// ---------------------------------------------------------------- transpose V
// V[4096][1024] f16 -> Vt[b][h][d=64][s=2048] f16
__global__ void transpose_v(const f16_t* __restrict__ V, f16_t* __restrict__ Vt)
{
    int s0 = blockIdx.x * 64;
    int y = blockIdx.y;                 // bh: b = y>>4, h = y&15
    int b = y >> 4, h = y & 15;
    __shared__ f16_t t[64][65];
    int tx = threadIdx.x;
    for (int i = threadIdx.y; i < 64; i += 8)
        t[i][tx] = V[(size_t)(b * Seq + s0 + i) * Udim + h * Dh + tx];
    __syncthreads();
    // t[s][d]; write Vt rows over d, contiguous in s
    for (int i = threadIdx.y; i < 64; i += 8)
        Vt[((size_t)y * Dh + i) * Seq + s0 + tx] = t[tx][i];
}

// ---------------------------------------------------------------- attention
// LDS-staged K/V tiles + S^T/O^T register chaining. 4 waves, each 16 q rows.
// ALL loop bounds compile-time (round-4's runtime tmax spilled st/pf to
// scratch: VGPR_Count=64 + 860us). Diagonal block: mask, don't skip.
__global__ __launch_bounds__(256)
void attn3(const f16_t* __restrict__ Q, const f16_t* __restrict__ K,
           const f16_t* __restrict__ Vt, float* __restrict__ O)
{
    int qtile = blockIdx.x, h = blockIdx.y, b = blockIdx.z;
    int tid = threadIdx.x;
    int w = tid >> 6, lane = tid & 63, quad = lane >> 4, l16 = lane & 15;
    int q0 = qtile * 64 + w * 16;                 // this wave's q rows
    int qidx = q0 + l16;                          // this lane's q row
    size_t bS = (size_t)b * Seq;

    __shared__ f16_t Ks[64][72];   // [kv][d]
    __shared__ f16_t Vs[64][72];   // [d][kv]

    // Q B-fragments (16x16x32): B[k=d=s*32+quad*8+j][n=q=l16]
    const f16_t* Qp = Q + (bS + qidx) * Udim + h * Dh;
    f16x8 qf[2];
#pragma unroll
    for (int s = 0; s < 2; s++) qf[s] = *(const f16x8*)(Qp + s * 32 + quad * 8);

    const f16_t* Kg = K + bS * Udim + h * Dh;
    const f16_t* Vg = Vt + ((size_t)(b * Hn + h)) * Dh * Seq;

    f32x4 Oacc[4] = {};          // O^T tiles: d = dt*16+quad*4+r, q = l16
    float m = -1e30f, l = 0.0f;  // per-lane: one q row

    int sr = tid >> 2, sc = (tid & 3) * 16;
    for (int kv0 = 0; kv0 <= qtile * 64; kv0 += 64) {
        // stage K-tile [kv][d] and V-tile [d][kv] (both coalesced 32B/thread)
        {
            const f16_t* kp = Kg + (size_t)(kv0 + sr) * Udim + sc;
            f16x8 k0 = *(const f16x8*)kp;
            f16x8 k1 = *(const f16x8*)(kp + 8);
            const f16_t* vp = Vg + (size_t)sr * Seq + kv0 + sc;
            f16x8 v0 = *(const f16x8*)vp;
            f16x8 v1 = *(const f16x8*)(vp + 8);
            *(f16x8*)&Ks[sr][sc] = k0;
            *(f16x8*)&Ks[sr][sc + 8] = k1;
            *(f16x8*)&Vs[sr][sc] = v0;
            *(f16x8*)&Vs[sr][sc + 8] = v1;
        }
        __syncthreads();

        bool diag = (kv0 == qtile * 64);

        // S^T tiles: A=K[m=kv][k=d] from LDS, B=Q^T from regs
        f32x4 st[4];
#pragma unroll
        for (int t = 0; t < 4; t++) {
            f32x4 a = {};
#pragma unroll
            for (int s = 0; s < 2; s++) {
                f16x8 kf = *(const f16x8*)&Ks[t * 16 + l16][s * 32 + quad * 8];
                a = __builtin_amdgcn_mfma_f32_16x16x32_f16(kf, qf[s], a, 0, 0, 0);
            }
            st[t] = a;
        }

        // softmax: row = q = l16 (per-lane scalar state)
        float mx = -1e30f;
#pragma unroll
        for (int t = 0; t < 4; t++)
#pragma unroll
            for (int r = 0; r < 4; r++) {
                float sv = st[t][r] * 0.125f;
                if (diag && (kv0 + t * 16 + quad * 4 + r > qidx))
                    sv = -1e30f;     // causal (off-diagonal blocks never masked)
                st[t][r] = sv;
                mx = fmaxf(mx, sv);
            }
        mx = fmaxf(mx, __shfl_xor(mx, 16));
        mx = fmaxf(mx, __shfl_xor(mx, 32));
        float mnew = fmaxf(m, mx);
        float alpha = __expf(m - mnew);
        float sum = 0.0f;
        f16x4 pf[4];
#pragma unroll
        for (int t = 0; t < 4; t++)
#pragma unroll
            for (int r = 0; r < 4; r++) {
                float p = __expf(st[t][r] - mnew);
                sum += p;
                pf[t][r] = (f16_t)p;   // P^T B-fragment, direct from C layout
            }
        sum += __shfl_xor(sum, 16);
        sum += __shfl_xor(sum, 32);
        l = l * alpha + sum;
        m = mnew;
#pragma unroll
        for (int dt = 0; dt < 4; dt++)
#pragma unroll
            for (int r = 0; r < 4; r++) Oacc[dt][r] *= alpha;

        // O^T += V^T . P^T : A = Vs[m=d][k=kv] from LDS
#pragma unroll
        for (int dt = 0; dt < 4; dt++) {
#pragma unroll
            for (int t = 0; t < 4; t++) {
                f16x4 vf = *(const f16x4*)&Vs[dt * 16 + l16][t * 16 + quad * 4];
                Oacc[dt] = __builtin_amdgcn_mfma_f32_16x16x16f16(vf, pf[t], Oacc[dt], 0, 0, 0);
            }
        }
        __syncthreads();   // LDS reads done before next staging
    }

    // epilogue: lane holds O^T[d=dt*16+quad*4+(0..3)][q=l16] -> float4 stores
    float invl = 1.0f / l;
    float* Op = O + (bS + qidx) * Udim + h * Dh;
#pragma unroll
    for (int dt = 0; dt < 4; dt++) {
        f32x4 o = Oacc[dt] * invl;
        *(f32x4*)(Op + dt * 16 + quad * 4) = o;
    }
}

// ---------------------------------------------------------------- LN stats
__global__ __launch_bounds__(256)
void ln_stats(const float* __restrict__ attn, const float* __restrict__ X,
              float* __restrict__ stats)
{
    int b = blockIdx.y;
    int base = b * PerBatch + blockIdx.x * 2048 + threadIdx.x * 8;
    float s = 0.0f, ss = 0.0f;
    for (int v = 0; v < 2; v++) {
        float4 a = *(const float4*)(attn + base + v * 4);
        float4 x = *(const float4*)(X + base + v * 4);
        float t0 = a.x + x.x, t1 = a.y + x.y, t2 = a.z + x.z, t3 = a.w + x.w;
        s += t0 + t1 + t2 + t3;
        ss += t0 * t0 + t1 * t1 + t2 * t2 + t3 * t3;
    }
    for (int o = 1; o < 64; o <<= 1) { s += __shfl_xor(s, o); ss += __shfl_xor(ss, o); }
    __shared__ float red[8];
    int wave = threadIdx.x >> 6, lane = threadIdx.x & 63;
    if (lane == 0) { red[wave] = s; red[4 + wave] = ss; }
    __syncthreads();
    if (threadIdx.x == 0) {
        atomicAdd(&stats[b], red[0] + red[1] + red[2] + red[3]);
        atomicAdd(&stats[2 + b], red[4] + red[5] + red[6] + red[7]);
    }
}

// ---------------------------------------------------------------- LN apply
__global__ __launch_bounds__(256)
void ln_norm(const float* __restrict__ attn, const float* __restrict__ X,
             const float* __restrict__ gamma, const float* __restrict__ beta,
             const float* __restrict__ stats, float* __restrict__ out)
{
    constexpr int TOT4 = Bsz * Seq * Udim / 4;   // 1M float4
    constexpr float invN = 1.0f / (float)PerBatch;
    float mu[2], inv[2];
    for (int b = 0; b < 2; b++) {
        float m = stats[b] * invN;
        float var = stats[2 + b] * invN - m * m;
        mu[b] = m;
        inv[b] = rsqrtf(var + 1e-5f);
    }
    for (int i = blockIdx.x * blockDim.x + threadIdx.x; i < TOT4;
         i += gridDim.x * blockDim.x) {
        int f = i * 4;
        int b = f >> 21;
        int su = f & (PerBatch - 1);
        float4 a = *(const float4*)(attn + f);
        float4 x = *(const float4*)(X + f);
        float4 g = *(const float4*)(gamma + su);
        float4 be = *(const float4*)(beta + su);
        float4 o;
        o.x = (a.x + x.x - mu[b]) * inv[b] * g.x + be.x;
        o.y = (a.y + x.y - mu[b]) * inv[b] * g.y + be.y;
        o.z = (a.z + x.z - mu[b]) * inv[b] * g.z + be.z;
        o.w = (a.w + x.w - mu[b]) * inv[b] * g.w + be.w;
        *(float4*)(out + f) = o;
    }
}

// ---------------------------------------------------------------- launch
extern "C" void kernel_launch(void* const* d_in, const int* in_sizes, int n_in,
                              void* d_out, int out_size, void* d_ws, size_t ws_size,
                              hipStream_t stream)
{
    const float* X     = (const float*)d_in[0];
    const float* Wq    = (const float*)d_in[1];
    const float* bq    = (const float*)d_in[2];
    const float* Wk    = (const float*)d_in[3];
    const float* bk    = (const float*)d_in[4];
    const float* Wv    = (const float*)d_in[5];
    const float* bv    = (const float*)d_in[6];
    const float* gamma = (const float*)d_in[7];
    const float* beta  = (const float*)d_in[8];
    float* out = (float*)d_out;

    char* ws = (char*)d_ws;
    size_t off = 0;
    auto alloc = [&](size_t bytes) -> void* {
        void* p = ws + off;
        off += (bytes + 255) & ~(size_t)255;
        return p;
    };
    bf16_t* Xb = (bf16_t*)alloc((size_t)Mrows * Cdim * 2);
    bf16_t* Tq = (bf16_t*)alloc((size_t)Cdim * Udim * 2);
    bf16_t* Tk = (bf16_t*)alloc((size_t)Cdim * Udim * 2);
    bf16_t* Tv = (bf16_t*)alloc((size_t)Cdim * Udim * 2);
    f16_t*  Qb = (f16_t*)alloc((size_t)Mrows * Udim * 2);
    f16_t*  Kb = (f16_t*)alloc((size_t)Mrows * Udim * 2);
    f16_t*  Vb = (f16_t*)alloc((size_t)Mrows * Udim * 2);
    f16_t*  Vtb = (f16_t*)alloc((size_t)Mrows * Udim * 2);
    float*  Ab = (float*)alloc((size_t)Mrows * Udim * 4);
    float*  stats = (float*)alloc(4 * sizeof(float));

    hipMemsetAsync(stats, 0, 4 * sizeof(float), stream);
    cast_x<<<dim3(Mrows * Cdim / 4 / 256), 256, 0, stream>>>(X, Xb);
    transpose_w<<<dim3(16, 16, 3), dim3(64, 8), 0, stream>>>(Wq, Wk, Wv, Tq, Tk, Tv);
    gemm_qkv<<<dim3(8, 32, 3), 256, 0, stream>>>(Xb, Tq, Tk, Tv, bq, bk, bv, Qb, Kb, Vb);
    transpose_v<<<dim3(Seq / 64, Bsz * Hn), dim3(64, 8), 0, stream>>>(Vb, Vtb);
    attn3<<<dim3(Seq / 64, Hn, Bsz), 256, 0, stream>>>(Qb, Kb, Vtb, Ab);
    ln_stats<<<dim3(1024, 2), 256, 0, stream>>>(Ab, X, stats);
    ln_norm<<<dim3(1024), 256, 0, stream>>>(Ab, X, gamma, beta, stats, out);
}

// Round 6
// 216.369 us; speedup vs baseline: 4.9478x; 1.4368x over previous
//
#include <hip/hip_runtime.h>
#include <hip/hip_bf16.h>

// Problem: B=2, S=2048, C=U=1024, H=16, dh=64. I/O FP32.
// cast X->bf16, transpose+cast W->bf16, QKV GEMM (m97-style global_load_lds
// staging, bf16 MFMA, f16 out), transpose V, flash attention (paired qtiles
// for load balance, LDS K/V tiles, S^T/O^T register chaining, fused residual
// + LN-stats in epilogue), LN apply.

typedef __bf16 bf16_t;
typedef __bf16 bf16x8 __attribute__((ext_vector_type(8)));
typedef __bf16 bf16x4 __attribute__((ext_vector_type(4)));
typedef _Float16 f16_t;
typedef _Float16 f16x4 __attribute__((ext_vector_type(4)));
typedef _Float16 f16x8 __attribute__((ext_vector_type(8)));
typedef float f32x4 __attribute__((ext_vector_type(4)));

constexpr int Bsz = 2;
constexpr int Seq = 2048;
constexpr int Cdim = 1024;   // == U
constexpr int Udim = 1024;
constexpr int Hn = 16;
constexpr int Dh = 64;
constexpr int Mrows = Bsz * Seq;          // 4096
constexpr int PerBatch = Seq * Udim;      // 2^21

// async global->LDS, 16B per lane; LDS dest = wave-uniform base + lane*16
__device__ __forceinline__ void gload16(const void* g, void* l)
{
    __builtin_amdgcn_global_load_lds(
        (const __attribute__((address_space(1))) void*)g,
        (__attribute__((address_space(3))) void*)l, 16, 0, 0);
}

// ---------------------------------------------------------------- cast X
__global__ __launch_bounds__(256)
void cast_x(const float* __restrict__ X, bf16_t* __restrict__ Xb)
{
    int i = blockIdx.x * 256 + threadIdx.x;     // over float4 groups, 1M total
    float4 v = ((const float4*)X)[i];
    bf16x4 o = { (bf16_t)v.x, (bf16_t)v.y, (bf16_t)v.z, (bf16_t)v.w };
    *(bf16x4*)(Xb + (size_t)i * 4) = o;
}

// ---------------------------------------------------------------- transpose W
__global__ void transpose_w(const float* __restrict__ Wq, const float* __restrict__ Wk,
                            const float* __restrict__ Wv,
                            bf16_t* __restrict__ Tq, bf16_t* __restrict__ Tk,
                            bf16_t* __restrict__ Tv)
{
    int z = blockIdx.z;
    const float* W = (z == 0) ? Wq : (z == 1) ? Wk : Wv;
    bf16_t* T = (z == 0) ? Tq : (z == 1) ? Tk : Tv;
    __shared__ bf16_t t[64][65];
    int x0 = blockIdx.x * 64, y0 = blockIdx.y * 64;
    int tx = threadIdx.x;
    for (int i = threadIdx.y; i < 64; i += 8)
        t[i][tx] = (bf16_t)W[(size_t)(y0 + i) * Cdim + x0 + tx];
    __syncthreads();
    for (int i = threadIdx.y; i < 64; i += 8)
        T[(size_t)(x0 + i) * Cdim + y0 + tx] = t[tx][i];
}

// ---------------------------------------------------------------- QKV GEMM
// m97 structure: 128x128 tile, BK=32, unpadded LDS, global_load_lds width 16.
__global__ __launch_bounds__(256)
void gemm_qkv(const bf16_t* __restrict__ X,
              const bf16_t* __restrict__ Wt0, const bf16_t* __restrict__ Wt1,
              const bf16_t* __restrict__ Wt2,
              const float* __restrict__ b0, const float* __restrict__ b1,
              const float* __restrict__ b2,
              f16_t* __restrict__ O0, f16_t* __restrict__ O1, f16_t* __restrict__ O2)
{
    int z = blockIdx.z;
    const bf16_t* Wt = (z == 0) ? Wt0 : (z == 1) ? Wt1 : Wt2;
    const float* bias = (z == 0) ? b0 : (z == 1) ? b1 : b2;
    f16_t* Og = (z == 0) ? O0 : (z == 1) ? O1 : O2;

    constexpr int Kd = 1024, Nd = 1024;
    __shared__ __align__(16) bf16_t As[128 * 32];   // unpadded: global_load_lds layout
    __shared__ __align__(16) bf16_t Bs[128 * 32];

    int tid = threadIdx.x;
    int wave = tid >> 6, lane = tid & 63, quad = lane >> 4, l16 = lane & 15;
    int wm = (wave & 1) * 64, wn = (wave >> 1) * 64;
    int m0 = blockIdx.y * 128, n0 = blockIdx.x * 128;

    f32x4 acc[4][4] = {};

    // staging geometry: element e = call*2048 + wave*512 + lane*8 within tile;
    // row = e/32 (32 bf16 per row), col = e%32
    int e0 = wave * 512 + lane * 8;
    int r0 = e0 >> 5, c0 = e0 & 31;
    int e1 = e0 + 2048;
    int r1 = e1 >> 5, c1 = e1 & 31;
    const bf16_t* Ag = X + (size_t)m0 * Kd;
    const bf16_t* Bg = Wt + (size_t)n0 * Kd;
    bf16_t* AsW0 = As + wave * 512;          // wave-uniform LDS bases
    bf16_t* AsW1 = As + 2048 + wave * 512;
    bf16_t* BsW0 = Bs + wave * 512;
    bf16_t* BsW1 = Bs + 2048 + wave * 512;

    for (int k0 = 0; k0 < Kd; k0 += 32) {
        gload16(Ag + (size_t)r0 * Kd + k0 + c0, AsW0);
        gload16(Ag + (size_t)r1 * Kd + k0 + c1, AsW1);
        gload16(Bg + (size_t)r0 * Kd + k0 + c0, BsW0);
        gload16(Bg + (size_t)r1 * Kd + k0 + c1, BsW1);
        __syncthreads();

        bf16x8 af[4], bfr[4];
#pragma unroll
        for (int i = 0; i < 4; i++)
            af[i] = *(const bf16x8*)&As[(wm + i * 16 + l16) * 32 + quad * 8];
#pragma unroll
        for (int i = 0; i < 4; i++)
            bfr[i] = *(const bf16x8*)&Bs[(wn + i * 16 + l16) * 32 + quad * 8];
#pragma unroll
        for (int mt = 0; mt < 4; mt++)
#pragma unroll
            for (int nt = 0; nt < 4; nt++)
                acc[mt][nt] = __builtin_amdgcn_mfma_f32_16x16x32_bf16(
                    af[mt], bfr[nt], acc[mt][nt], 0, 0, 0);
        __syncthreads();
    }

    // epilogue: C/D layout col=lane&15, row=quad*4+reg
#pragma unroll
    for (int nt = 0; nt < 4; nt++) {
        int col = n0 + wn + nt * 16 + l16;
        float bv = bias[col];
#pragma unroll
        for (int mt = 0; mt < 4; mt++) {
            int row = m0 + wm + mt * 16 + quad * 4;
#pragma unroll
            for (int r = 0; r < 4; r++)
                Og[(size_t)(row + r) * Nd + col] = (f16_t)(acc[mt][nt][r] + bv);
        }
    }
}

// ---------------------------------------------------------------- transpose V
// V[4096][1024] f16 -> Vt[b][h][d=64][s=2048] f16
__global__ void transpose_v(const f16_t* __restrict__ V, f16_t* __restrict__ Vt)
{
    int s0 = blockIdx.x * 64;
    int y = blockIdx.y;                 // bh: b = y>>4, h = y&15
    int b = y >> 4, h = y & 15;
    __shared__ f16_t t[64][65];
    int tx = threadIdx.x;
    for (int i = threadIdx.y; i < 64; i += 8)
        t[i][tx] = V[(size_t)(b * Seq + s0 + i) * Udim + h * Dh + tx];
    __syncthreads();
    for (int i = threadIdx.y; i < 64; i += 8)
        Vt[((size_t)y * Dh + i) * Seq + s0 + tx] = t[tx][i];
}

// ---------------------------------------------------------------- attention
// Paired qtiles (p, 31-p): every block = exactly 33 kv-iters (load balance).
// LDS K/V tiles + S^T/O^T register chaining, static loop bounds. Epilogue
// fuses residual (+X) and per-batch sum/sumsq stats (atomics per block).
__global__ __launch_bounds__(256)
void attn4(const f16_t* __restrict__ Q, const f16_t* __restrict__ K,
           const f16_t* __restrict__ Vt, const float* __restrict__ X,
           float* __restrict__ R, float* __restrict__ stats)
{
    int p = blockIdx.x, h = blockIdx.y, b = blockIdx.z;
    int tid = threadIdx.x;
    int w = tid >> 6, lane = tid & 63, quad = lane >> 4, l16 = lane & 15;
    size_t bS = (size_t)b * Seq;

    __shared__ f16_t Ks[64][72];   // [kv][d]
    __shared__ f16_t Vs[64][72];   // [d][kv]

    const f16_t* Kg = K + bS * Udim + h * Dh;
    const f16_t* Vg = Vt + ((size_t)(b * Hn + h)) * Dh * Seq;

    float s_acc = 0.0f, ss_acc = 0.0f;
    int sr = tid >> 2, sc = (tid & 3) * 16;

#pragma unroll
    for (int pass = 0; pass < 2; pass++) {
        int qtile = pass ? (31 - p) : p;
        int q0 = qtile * 64 + w * 16;
        int qidx = q0 + l16;

        const f16_t* Qp = Q + (bS + qidx) * Udim + h * Dh;
        f16x8 qf[2];
#pragma unroll
        for (int s = 0; s < 2; s++) qf[s] = *(const f16x8*)(Qp + s * 32 + quad * 8);

        f32x4 Oacc[4] = {};
        float m = -1e30f, l = 0.0f;

        for (int kv0 = 0; kv0 <= qtile * 64; kv0 += 64) {
            {
                const f16_t* kp = Kg + (size_t)(kv0 + sr) * Udim + sc;
                f16x8 k0 = *(const f16x8*)kp;
                f16x8 k1 = *(const f16x8*)(kp + 8);
                const f16_t* vp = Vg + (size_t)sr * Seq + kv0 + sc;
                f16x8 v0 = *(const f16x8*)vp;
                f16x8 v1 = *(const f16x8*)(vp + 8);
                *(f16x8*)&Ks[sr][sc] = k0;
                *(f16x8*)&Ks[sr][sc + 8] = k1;
                *(f16x8*)&Vs[sr][sc] = v0;
                *(f16x8*)&Vs[sr][sc + 8] = v1;
            }
            __syncthreads();

            bool diag = (kv0 == qtile * 64);

            f32x4 st[4];
#pragma unroll
            for (int t = 0; t < 4; t++) {
                f32x4 a = {};
#pragma unroll
                for (int s = 0; s < 2; s++) {
                    f16x8 kf = *(const f16x8*)&Ks[t * 16 + l16][s * 32 + quad * 8];
                    a = __builtin_amdgcn_mfma_f32_16x16x32_f16(kf, qf[s], a, 0, 0, 0);
                }
                st[t] = a;
            }

            float mx = -1e30f;
#pragma unroll
            for (int t = 0; t < 4; t++)
#pragma unroll
                for (int r = 0; r < 4; r++) {
                    float sv = st[t][r] * 0.125f;
                    if (diag && (kv0 + t * 16 + quad * 4 + r > qidx))
                        sv = -1e30f;     // causal
                    st[t][r] = sv;
                    mx = fmaxf(mx, sv);
                }
            mx = fmaxf(mx, __shfl_xor(mx, 16));
            mx = fmaxf(mx, __shfl_xor(mx, 32));
            float mnew = fmaxf(m, mx);
            float alpha = __expf(m - mnew);
            float sum = 0.0f;
            f16x4 pf[4];
#pragma unroll
            for (int t = 0; t < 4; t++)
#pragma unroll
                for (int r = 0; r < 4; r++) {
                    float pv = __expf(st[t][r] - mnew);
                    sum += pv;
                    pf[t][r] = (f16_t)pv;
                }
            sum += __shfl_xor(sum, 16);
            sum += __shfl_xor(sum, 32);
            l = l * alpha + sum;
            m = mnew;
#pragma unroll
            for (int dt = 0; dt < 4; dt++)
#pragma unroll
                for (int r = 0; r < 4; r++) Oacc[dt][r] *= alpha;

#pragma unroll
            for (int dt = 0; dt < 4; dt++) {
#pragma unroll
                for (int t = 0; t < 4; t++) {
                    f16x4 vf = *(const f16x4*)&Vs[dt * 16 + l16][t * 16 + quad * 4];
                    Oacc[dt] = __builtin_amdgcn_mfma_f32_16x16x16f16(vf, pf[t], Oacc[dt], 0, 0, 0);
                }
            }
            __syncthreads();
        }

        // epilogue: resid = O/l + X ; accumulate stats
        float invl = 1.0f / l;
        const float* Xp = X + (bS + qidx) * Udim + h * Dh;
        float* Rp = R + (bS + qidx) * Udim + h * Dh;
#pragma unroll
        for (int dt = 0; dt < 4; dt++) {
            f32x4 xv = *(const f32x4*)(Xp + dt * 16 + quad * 4);
            f32x4 o = Oacc[dt] * invl + xv;
            *(f32x4*)(Rp + dt * 16 + quad * 4) = o;
#pragma unroll
            for (int r = 0; r < 4; r++) {
                s_acc += o[r];
                ss_acc += o[r] * o[r];
            }
        }
    }

    // block-level stats reduction -> 2 atomics
#pragma unroll
    for (int o = 1; o < 64; o <<= 1) {
        s_acc += __shfl_xor(s_acc, o);
        ss_acc += __shfl_xor(ss_acc, o);
    }
    __shared__ float red[8];
    if (lane == 0) { red[w] = s_acc; red[4 + w] = ss_acc; }
    __syncthreads();
    if (tid == 0) {
        atomicAdd(&stats[b], red[0] + red[1] + red[2] + red[3]);
        atomicAdd(&stats[2 + b], red[4] + red[5] + red[6] + red[7]);
    }
}

// ---------------------------------------------------------------- LN apply
__global__ __launch_bounds__(256)
void ln_norm(const float* __restrict__ R, const float* __restrict__ gamma,
             const float* __restrict__ beta, const float* __restrict__ stats,
             float* __restrict__ out)
{
    constexpr int TOT4 = Bsz * Seq * Udim / 4;   // 1M float4
    constexpr float invN = 1.0f / (float)PerBatch;
    float mu[2], inv[2];
    for (int b = 0; b < 2; b++) {
        float m = stats[b] * invN;
        float var = stats[2 + b] * invN - m * m;
        mu[b] = m;
        inv[b] = rsqrtf(var + 1e-5f);
    }
    for (int i = blockIdx.x * blockDim.x + threadIdx.x; i < TOT4;
         i += gridDim.x * blockDim.x) {
        int f = i * 4;
        int b = f >> 21;
        int su = f & (PerBatch - 1);
        float4 rv = *(const float4*)(R + f);
        float4 g = *(const float4*)(gamma + su);
        float4 be = *(const float4*)(beta + su);
        float4 o;
        o.x = (rv.x - mu[b]) * inv[b] * g.x + be.x;
        o.y = (rv.y - mu[b]) * inv[b] * g.y + be.y;
        o.z = (rv.z - mu[b]) * inv[b] * g.z + be.z;
        o.w = (rv.w - mu[b]) * inv[b] * g.w + be.w;
        *(float4*)(out + f) = o;
    }
}

// ---------------------------------------------------------------- launch
extern "C" void kernel_launch(void* const* d_in, const int* in_sizes, int n_in,
                              void* d_out, int out_size, void* d_ws, size_t ws_size,
                              hipStream_t stream)
{
    const float* X     = (const float*)d_in[0];
    const float* Wq    = (const float*)d_in[1];
    const float* bq    = (const float*)d_in[2];
    const float* Wk    = (const float*)d_in[3];
    const float* bk    = (const float*)d_in[4];
    const float* Wv    = (const float*)d_in[5];
    const float* bv    = (const float*)d_in[6];
    const float* gamma = (const float*)d_in[7];
    const float* beta  = (const float*)d_in[8];
    float* out = (float*)d_out;

    char* ws = (char*)d_ws;
    size_t off = 0;
    auto alloc = [&](size_t bytes) -> void* {
        void* p = ws + off;
        off += (bytes + 255) & ~(size_t)255;
        return p;
    };
    bf16_t* Xb = (bf16_t*)alloc((size_t)Mrows * Cdim * 2);
    bf16_t* Tq = (bf16_t*)alloc((size_t)Cdim * Udim * 2);
    bf16_t* Tk = (bf16_t*)alloc((size_t)Cdim * Udim * 2);
    bf16_t* Tv = (bf16_t*)alloc((size_t)Cdim * Udim * 2);
    f16_t*  Qb = (f16_t*)alloc((size_t)Mrows * Udim * 2);
    f16_t*  Kb = (f16_t*)alloc((size_t)Mrows * Udim * 2);
    f16_t*  Vb = (f16_t*)alloc((size_t)Mrows * Udim * 2);
    f16_t*  Vtb = (f16_t*)alloc((size_t)Mrows * Udim * 2);
    float*  Rb = (float*)alloc((size_t)Mrows * Udim * 4);
    float*  stats = (float*)alloc(4 * sizeof(float));

    hipMemsetAsync(stats, 0, 4 * sizeof(float), stream);
    cast_x<<<dim3(Mrows * Cdim / 4 / 256), 256, 0, stream>>>(X, Xb);
    transpose_w<<<dim3(16, 16, 3), dim3(64, 8), 0, stream>>>(Wq, Wk, Wv, Tq, Tk, Tv);
    gemm_qkv<<<dim3(8, 32, 3), 256, 0, stream>>>(Xb, Tq, Tk, Tv, bq, bk, bv, Qb, Kb, Vb);
    transpose_v<<<dim3(Seq / 64, Bsz * Hn), dim3(64, 8), 0, stream>>>(Vb, Vtb);
    attn4<<<dim3(16, Hn, Bsz), 256, 0, stream>>>(Qb, Kb, Vtb, X, Rb, stats);
    ln_norm<<<dim3(1024), 256, 0, stream>>>(Rb, gamma, beta, stats, out);
}